// Round 1
// baseline (931.855 us; speedup 1.0000x reference)
//
#include <hip/hip_runtime.h>

typedef unsigned short u16;
typedef unsigned int u32;
typedef float f32x4 __attribute__((ext_vector_type(4)));
typedef __bf16 bf16x8 __attribute__((ext_vector_type(8)));

#define DEV __device__ __forceinline__

DEV u16 f2b(float f) {
    union { float f; u32 u; } v; v.f = f;
    u32 r = v.u + 0x7fffu + ((v.u >> 16) & 1u);   // RNE
    return (u16)(r >> 16);
}
DEV float b2f(u16 b) {
    union { u32 u; float f; } v; v.u = ((u32)b) << 16;
    return v.f;
}

// global -> LDS direct (16B/lane). LDS dest must be wave-uniform base; HW adds lane*16.
DEV void gload16(const void* g, void* l) {
    __builtin_amdgcn_global_load_lds((const __attribute__((address_space(1))) void*)g,
                                     (__attribute__((address_space(3))) void*)l, 16, 0, 0);
}

DEV f32x4 mfma16(bf16x8 a, bf16x8 b, f32x4 c) {
    return __builtin_amdgcn_mfma_f32_16x16x32_bf16(a, b, c, 0, 0, 0);
}

// ---------------------------------------------------------------- convert x
__global__ __launch_bounds__(256) void convx_kernel(const float* __restrict__ in,
                                                    u16* __restrict__ out) {
    size_t i = ((size_t)blockIdx.x * 256 + threadIdx.x) * 4;
    float4 v = *(const float4*)(in + i);
    ushort4 o; o.x = f2b(v.x); o.y = f2b(v.y); o.z = f2b(v.z); o.w = f2b(v.w);
    *(ushort4*)(out + i) = o;
}

// ------------------------------------------- transpose + convert: (KxN f32) -> (NxK bf16)
__global__ __launch_bounds__(256) void tconv_kernel(const float* __restrict__ in,
                                                    u16* __restrict__ out, int K, int N) {
    __shared__ float tile[64][65];
    int t = threadIdx.x;
    int n0 = blockIdx.x * 64, k0 = blockIdx.y * 64;
    int r = t >> 4, c4 = (t & 15) * 4;
#pragma unroll
    for (int i = 0; i < 4; ++i) {
        float4 v = *(const float4*)(in + (size_t)(k0 + i * 16 + r) * N + n0 + c4);
        tile[i * 16 + r][c4 + 0] = v.x; tile[i * 16 + r][c4 + 1] = v.y;
        tile[i * 16 + r][c4 + 2] = v.z; tile[i * 16 + r][c4 + 3] = v.w;
    }
    __syncthreads();
#pragma unroll
    for (int i = 0; i < 4; ++i) {
        int nn = i * 16 + r;
        ushort4 o;
        o.x = f2b(tile[c4 + 0][nn]); o.y = f2b(tile[c4 + 1][nn]);
        o.z = f2b(tile[c4 + 2][nn]); o.w = f2b(tile[c4 + 3][nn]);
        *(ushort4*)(out + (size_t)(n0 + nn) * K + k0 + c4) = o;
    }
}

// ---------------------------------------------------------------- GEMM (A MxK, Bt NxK, both bf16)
// 128x128 tile, BK=64, 4 waves (2x2), 16x16x32 MFMA. m97 structure + source-side XOR swizzle.
template <bool F32OUT>
__global__ __launch_bounds__(256) void gemm_kernel(const u16* __restrict__ A,
                                                   const u16* __restrict__ Bt,
                                                   u16* __restrict__ Cb,
                                                   float* __restrict__ Cf,
                                                   int M, int N, int K) {
    __shared__ __align__(16) u16 As[128 * 64];
    __shared__ __align__(16) u16 Bs[128 * 64];
    int t = threadIdx.x;
    int lane = t & 63, w = t >> 6;
    int wr = w >> 1, wc = w & 1;
    int lr = lane & 15, hi = lane >> 4;
    int m0 = blockIdx.y * 128, n0 = blockIdx.x * 128;
    f32x4 acc[4][4] = {};
    int nk = K >> 6;
    for (int kt = 0; kt < nk; ++kt) {
        int k0 = kt << 6;
        // stage A and Bt tiles (128 rows x 64 cols each); source pre-swizzled for read-side XOR
#pragma unroll
        for (int i = 0; i < 4; ++i) {
            int c = i * 256 + t;
            int row = c >> 3;
            int col8 = ((c & 7) ^ (row & 7)) << 3;
            int ldsb = (i * 256 + (t & ~63)) * 16;   // wave-uniform base
            gload16(A + (size_t)(m0 + row) * K + k0 + col8, (char*)As + ldsb);
            gload16(Bt + (size_t)(n0 + row) * K + k0 + col8, (char*)Bs + ldsb);
        }
        asm volatile("s_waitcnt vmcnt(0)" ::: "memory");
        __syncthreads();
#pragma unroll
        for (int kk = 0; kk < 64; kk += 32) {
            bf16x8 af[4], bfr[4];
#pragma unroll
            for (int i2 = 0; i2 < 4; ++i2) {
                int row = wr * 64 + i2 * 16 + lr;
                int byt = (row * 128 + (kk + 8 * hi) * 2) ^ ((row & 7) << 4);
                af[i2] = *(const bf16x8*)((const char*)As + byt);
                int rowb = wc * 64 + i2 * 16 + lr;
                int bytb = (rowb * 128 + (kk + 8 * hi) * 2) ^ ((rowb & 7) << 4);
                bfr[i2] = *(const bf16x8*)((const char*)Bs + bytb);
            }
#pragma unroll
            for (int im = 0; im < 4; ++im)
#pragma unroll
                for (int jn = 0; jn < 4; ++jn)
                    acc[im][jn] = mfma16(af[im], bfr[jn], acc[im][jn]);
        }
        __syncthreads();
    }
#pragma unroll
    for (int im = 0; im < 4; ++im)
#pragma unroll
        for (int jn = 0; jn < 4; ++jn)
#pragma unroll
            for (int r = 0; r < 4; ++r) {
                int m = m0 + wr * 64 + im * 16 + hi * 4 + r;
                int n = n0 + wc * 64 + jn * 16 + lr;
                if (F32OUT) Cf[(size_t)m * N + n] = acc[im][jn][r];
                else        Cb[(size_t)m * N + n] = f2b(acc[im][jn][r]);
            }
}

// ---------------------------------------------------------------- RoPE (in-place bf16) + k f32 out
__global__ __launch_bounds__(256) void rope_kernel(u16* __restrict__ qb, u16* __restrict__ kb,
                                                   float* __restrict__ outk) {
    int row = blockIdx.y;                    // b*2048 + l
    int p = blockIdx.x * 256 + threadIdx.x;  // 0..2559: 32 q-heads + 8 kv-heads, 64 pairs each
    int b = row >> 11, l = row & 2047;
    if (p < 2048) {
        int h = p >> 6, i = p & 63;
        size_t idx = (size_t)row * 4096 + h * 128 + 2 * i;
        float freq = exp2f((float)i * -0.2076205059304601f);  // 10000^(-i/64)
        float sv, cv; sincosf((float)l * freq, &sv, &cv);
        u32 pr = *(const u32*)(qb + idx);
        float x1 = b2f((u16)(pr & 0xffff)), x2 = b2f((u16)(pr >> 16));
        float o1 = x1 * cv + x2 * sv, o2 = x1 * sv - x2 * cv;
        *(u32*)(qb + idx) = (u32)f2b(o1) | ((u32)f2b(o2) << 16);
    } else {
        int kvh = (p >> 6) - 32, i = p & 63;
        size_t idx = (size_t)row * 1024 + kvh * 128 + 2 * i;
        float freq = exp2f((float)i * -0.2076205059304601f);
        float sv, cv; sincosf((float)l * freq, &sv, &cv);
        u32 pr = *(const u32*)(kb + idx);
        float x1 = b2f((u16)(pr & 0xffff)), x2 = b2f((u16)(pr >> 16));
        float o1 = x1 * cv + x2 * sv, o2 = x1 * sv - x2 * cv;
        *(u32*)(kb + idx) = (u32)f2b(o1) | ((u32)f2b(o2) << 16);
#pragma unroll
        for (int r = 0; r < 4; ++r) {
            float2 o; o.x = o1; o.y = o2;
            *(float2*)(outk + ((size_t)((b * 32 + kvh * 4 + r) * 2048) + l) * 128 + 2 * i) = o;
        }
    }
}

// --------------------------------- V: write f32 x4 GQA copies to d_out + bf16 V^T for attention
__global__ __launch_bounds__(256) void vtrans_kernel(const u16* __restrict__ vb,
                                                     u16* __restrict__ vt,
                                                     float* __restrict__ outv) {
    __shared__ u16 tile[64][65];
    int t = threadIdx.x;
    int l0 = blockIdx.x * 64, d0 = blockIdx.y * 64;
    int z = blockIdx.z, b = z >> 3, kvh = z & 7;
    int r = t >> 4, c4 = (t & 15) * 4;
#pragma unroll
    for (int i = 0; i < 4; ++i) {
        int l = l0 + i * 16 + r;
        ushort4 v = *(const ushort4*)(vb + (size_t)(b * 2048 + l) * 1024 + kvh * 128 + d0 + c4);
        tile[i * 16 + r][c4 + 0] = v.x; tile[i * 16 + r][c4 + 1] = v.y;
        tile[i * 16 + r][c4 + 2] = v.z; tile[i * 16 + r][c4 + 3] = v.w;
        float4 f; f.x = b2f(v.x); f.y = b2f(v.y); f.z = b2f(v.z); f.w = b2f(v.w);
#pragma unroll
        for (int rr = 0; rr < 4; ++rr)
            *(float4*)(outv + ((size_t)((b * 32 + kvh * 4 + rr) * 2048) + l) * 128 + d0 + c4) = f;
    }
    __syncthreads();
#pragma unroll
    for (int i = 0; i < 4; ++i) {
        int dn = i * 16 + r;
        ushort4 o;
        o.x = tile[c4 + 0][dn]; o.y = tile[c4 + 1][dn];
        o.z = tile[c4 + 2][dn]; o.w = tile[c4 + 3][dn];
        *(ushort4*)(vt + (size_t)((b * 8 + kvh) * 128 + d0 + dn) * 2048 + l0 + c4) = o;
    }
}

// ---------------------------------------------------------------- flash attention
// grid (L/64, H, B); 4 waves x 16 q-rows. Q,K staged via gload_lds (swizzled source),
// V^T pre-transposed in global. Online softmax; P through per-wave LDS.
__global__ __launch_bounds__(256) void attn_kernel(const u16* __restrict__ qb,
                                                   const u16* __restrict__ kb,
                                                   const u16* __restrict__ vt,
                                                   u16* __restrict__ ab) {
    __shared__ __align__(16) u16 Ks[64 * 128];   // Q staging, then K tiles
    __shared__ __align__(16) u16 Vs[128 * 64];   // V^T tile [dh][kv]
    __shared__ __align__(16) u16 Ps[4][16 * 64]; // per-wave P
    int t = threadIdx.x, lane = t & 63, w = t >> 6;
    int lr = lane & 15, hi = lane >> 4;
    int qblk = blockIdx.x, h = blockIdx.y, b = blockIdx.z, kvh = h >> 2;
    int q0 = qblk * 64;

    // stage Q (64 x 128) into Ks
#pragma unroll
    for (int i = 0; i < 4; ++i) {
        int c = i * 256 + t;
        int row = c >> 4;
        int col8 = ((c & 15) ^ (row & 7)) << 3;
        gload16(qb + (size_t)(b * 2048 + q0 + row) * 4096 + h * 128 + col8,
                (char*)Ks + (i * 256 + (t & ~63)) * 16);
    }
    asm volatile("s_waitcnt vmcnt(0)" ::: "memory");
    __syncthreads();
    bf16x8 qf[4];
    int qr = w * 16 + lr;
#pragma unroll
    for (int kki = 0; kki < 4; ++kki) {
        int byt = (qr * 256 + (kki * 32 + 8 * hi) * 2) ^ ((qr & 7) << 4);
        qf[kki] = *(const bf16x8*)((const char*)Ks + byt);
    }
    __syncthreads();  // Q regs loaded; Ks free for K tiles

    f32x4 acc[8] = {};
    float mrun[4], lrun[4];
#pragma unroll
    for (int r = 0; r < 4; ++r) { mrun[r] = -1e30f; lrun[r] = 0.f; }

    for (int kt = 0; kt <= qblk; ++kt) {
        int k0 = kt * 64;
#pragma unroll
        for (int i = 0; i < 4; ++i) {  // K tile 64x128
            int c = i * 256 + t;
            int row = c >> 4;
            int col8 = ((c & 15) ^ (row & 7)) << 3;
            gload16(kb + (size_t)(b * 2048 + k0 + row) * 1024 + kvh * 128 + col8,
                    (char*)Ks + (i * 256 + (t & ~63)) * 16);
        }
#pragma unroll
        for (int i = 0; i < 4; ++i) {  // V^T tile 128x64
            int c = i * 256 + t;
            int row = c >> 3;
            int col8 = ((c & 7) ^ (row & 7)) << 3;
            gload16(vt + (size_t)((b * 8 + kvh) * 128 + row) * 2048 + k0 + col8,
                    (char*)Vs + (1024 * 16 + (i * 256 + (t & ~63)) * 16) - 1024 * 16);
        }
        asm volatile("s_waitcnt vmcnt(0)" ::: "memory");
        __syncthreads();

        // S = Q K^T
        f32x4 s[4] = {};
#pragma unroll
        for (int kki = 0; kki < 4; ++kki) {
            bf16x8 kf[4];
#pragma unroll
            for (int fc = 0; fc < 4; ++fc) {
                int kvr = fc * 16 + lr;
                int byt = (kvr * 256 + (kki * 32 + 8 * hi) * 2) ^ ((kvr & 7) << 4);
                kf[fc] = *(const bf16x8*)((const char*)Ks + byt);
            }
#pragma unroll
            for (int fc = 0; fc < 4; ++fc) s[fc] = mfma16(qf[kki], kf[fc], s[fc]);
        }
        const float SC = 0.08838834764831845f;  // 1/sqrt(128)
        int diag = (kt == qblk);
#pragma unroll
        for (int fc = 0; fc < 4; ++fc)
#pragma unroll
            for (int r = 0; r < 4; ++r) {
                float v = s[fc][r] * SC;
                if (diag && (fc * 16 + lr) > (w * 16 + hi * 4 + r)) v = -1e30f;
                s[fc][r] = v;
            }
        // online softmax
        float fr[4];
#pragma unroll
        for (int r = 0; r < 4; ++r) {
            float v = fmaxf(fmaxf(s[0][r], s[1][r]), fmaxf(s[2][r], s[3][r]));
            v = fmaxf(v, __shfl_xor(v, 1)); v = fmaxf(v, __shfl_xor(v, 2));
            v = fmaxf(v, __shfl_xor(v, 4)); v = fmaxf(v, __shfl_xor(v, 8));
            float mn = fmaxf(mrun[r], v);
            fr[r] = __expf(mrun[r] - mn);
            mrun[r] = mn;
        }
#pragma unroll
        for (int fc = 0; fc < 4; ++fc)
#pragma unroll
            for (int r = 0; r < 4; ++r) s[fc][r] = __expf(s[fc][r] - mrun[r]);
#pragma unroll
        for (int r = 0; r < 4; ++r) {
            float v = s[0][r] + s[1][r] + s[2][r] + s[3][r];
            v += __shfl_xor(v, 1); v += __shfl_xor(v, 2);
            v += __shfl_xor(v, 4); v += __shfl_xor(v, 8);
            lrun[r] = lrun[r] * fr[r] + v;
        }
#pragma unroll
        for (int dhf = 0; dhf < 8; ++dhf)
#pragma unroll
            for (int r = 0; r < 4; ++r) acc[dhf][r] *= fr[r];
        // P -> LDS (bf16, swizzled)
        u16* Pw = Ps[w];
#pragma unroll
        for (int fc = 0; fc < 4; ++fc)
#pragma unroll
            for (int r = 0; r < 4; ++r) {
                int prow = hi * 4 + r, pcol = fc * 16 + lr;
                int byt = (prow * 128 + pcol * 2) ^ ((prow & 7) << 4);
                *(u16*)((char*)Pw + byt) = f2b(s[fc][r]);
            }
        asm volatile("s_waitcnt lgkmcnt(0)" ::: "memory");
        // O += P V
#pragma unroll
        for (int kk2 = 0; kk2 < 2; ++kk2) {
            int bytp = (lr * 128 + (kk2 * 32 + 8 * hi) * 2) ^ ((lr & 7) << 4);
            bf16x8 pf = *(const bf16x8*)((const char*)Pw + bytp);
#pragma unroll
            for (int dhf = 0; dhf < 8; ++dhf) {
                int dh = dhf * 16 + lr;
                int bytv = (dh * 128 + (kk2 * 32 + 8 * hi) * 2) ^ ((dh & 7) << 4);
                bf16x8 vf = *(const bf16x8*)((const char*)Vs + bytv);
                acc[dhf] = mfma16(pf, vf, acc[dhf]);
            }
        }
        __syncthreads();
    }
#pragma unroll
    for (int dhf = 0; dhf < 8; ++dhf)
#pragma unroll
        for (int r = 0; r < 4; ++r) {
            int qrow = q0 + w * 16 + hi * 4 + r;
            int dh = dhf * 16 + lr;
            ab[(size_t)(b * 2048 + qrow) * 4096 + h * 128 + dh] = f2b(acc[dhf][r] / lrun[r]);
        }
}

// ---------------------------------------------------------------- launch
extern "C" void kernel_launch(void* const* d_in, const int* in_sizes, int n_in,
                              void* d_out, int out_size, void* d_ws, size_t ws_size,
                              hipStream_t stream) {
    (void)in_sizes; (void)n_in; (void)out_size; (void)ws_size;
    const float* x  = (const float*)d_in[0];
    // d_in[1] = mask: exact causal tril(0 / -1e9) — handled analytically in attn_kernel
    const float* wq = (const float*)d_in[2];
    const float* wk = (const float*)d_in[3];
    const float* wv = (const float*)d_in[4];
    const float* wo = (const float*)d_in[5];

    char* ws = (char*)d_ws;
    u16* xb  = (u16*)(ws + 0);           // 32 MiB (reused as ab later)
    u16* wqb = (u16*)(ws + 33554432);    // 32 MiB (reused as wob later)
    u16* wkb = (u16*)(ws + 67108864);    //  8 MiB
    u16* wvb = (u16*)(ws + 75497472);    //  8 MiB
    u16* qb  = (u16*)(ws + 83886080);    // 32 MiB
    u16* kb  = (u16*)(ws + 117440512);   //  8 MiB
    u16* vb  = (u16*)(ws + 125829120);   //  8 MiB
    u16* vt  = (u16*)(ws + 134217728);   //  8 MiB  -> total 136 MiB
    u16* ab  = xb;
    u16* wob = wqb;

    float* out0 = (float*)d_out;
    float* outk = out0 + 16777216;
    float* outv = out0 + 33554432;

    convx_kernel<<<16384, 256, 0, stream>>>(x, xb);
    tconv_kernel<<<dim3(64, 64), 256, 0, stream>>>(wq, wqb, 4096, 4096);
    tconv_kernel<<<dim3(16, 64), 256, 0, stream>>>(wk, wkb, 4096, 1024);
    tconv_kernel<<<dim3(16, 64), 256, 0, stream>>>(wv, wvb, 4096, 1024);

    gemm_kernel<false><<<dim3(32, 32), 256, 0, stream>>>(xb, wqb, qb, nullptr, 4096, 4096, 4096);
    tconv_kernel<<<dim3(64, 64), 256, 0, stream>>>(wo, wob, 4096, 4096);  // after gemm-q freed wqb
    gemm_kernel<false><<<dim3(8, 32), 256, 0, stream>>>(xb, wkb, kb, nullptr, 4096, 1024, 4096);
    gemm_kernel<false><<<dim3(8, 32), 256, 0, stream>>>(xb, wvb, vb, nullptr, 4096, 1024, 4096);

    rope_kernel<<<dim3(10, 4096), 256, 0, stream>>>(qb, kb, outk);
    vtrans_kernel<<<dim3(32, 2, 16), 256, 0, stream>>>(vb, vt, outv);

    attn_kernel<<<dim3(32, 32, 2), 256, 0, stream>>>(qb, kb, vt, ab);

    gemm_kernel<true><<<dim3(32, 32), 256, 0, stream>>>(ab, wob, nullptr, out0, 4096, 4096, 4096);
}

// Round 2
// 702.915 us; speedup vs baseline: 1.3257x; 1.3257x over previous
//
#include <hip/hip_runtime.h>

typedef unsigned short u16;
typedef unsigned int u32;
typedef float f32x4 __attribute__((ext_vector_type(4)));
typedef __bf16 bf16x8 __attribute__((ext_vector_type(8)));

#define DEV __device__ __forceinline__

DEV u16 f2b(float f) {
    union { float f; u32 u; } v; v.f = f;
    u32 r = v.u + 0x7fffu + ((v.u >> 16) & 1u);   // RNE
    return (u16)(r >> 16);
}
DEV float b2f(u16 b) {
    union { u32 u; float f; } v; v.u = ((u32)b) << 16;
    return v.f;
}

// global -> LDS direct (16B/lane). LDS dest must be wave-uniform base; HW adds lane*16.
DEV void gload16(const void* g, void* l) {
    __builtin_amdgcn_global_load_lds((const __attribute__((address_space(1))) void*)g,
                                     (__attribute__((address_space(3))) void*)l, 16, 0, 0);
}

DEV f32x4 mfma16(bf16x8 a, bf16x8 b, f32x4 c) {
    return __builtin_amdgcn_mfma_f32_16x16x32_bf16(a, b, c, 0, 0, 0);
}

// ---------------------------------------------------------------- convert x
__global__ __launch_bounds__(256) void convx_kernel(const float* __restrict__ in,
                                                    u16* __restrict__ out) {
    size_t i = ((size_t)blockIdx.x * 256 + threadIdx.x) * 4;
    float4 v = *(const float4*)(in + i);
    ushort4 o; o.x = f2b(v.x); o.y = f2b(v.y); o.z = f2b(v.z); o.w = f2b(v.w);
    *(ushort4*)(out + i) = o;
}

// ------------------------------------------- transpose + convert: (KxN f32) -> (NxK bf16)
__global__ __launch_bounds__(256) void tconv_kernel(const float* __restrict__ in,
                                                    u16* __restrict__ out, int K, int N) {
    __shared__ float tile[64][65];
    int t = threadIdx.x;
    int n0 = blockIdx.x * 64, k0 = blockIdx.y * 64;
    int r = t >> 4, c4 = (t & 15) * 4;
#pragma unroll
    for (int i = 0; i < 4; ++i) {
        float4 v = *(const float4*)(in + (size_t)(k0 + i * 16 + r) * N + n0 + c4);
        tile[i * 16 + r][c4 + 0] = v.x; tile[i * 16 + r][c4 + 1] = v.y;
        tile[i * 16 + r][c4 + 2] = v.z; tile[i * 16 + r][c4 + 3] = v.w;
    }
    __syncthreads();
#pragma unroll
    for (int i = 0; i < 4; ++i) {
        int nn = i * 16 + r;
        ushort4 o;
        o.x = f2b(tile[c4 + 0][nn]); o.y = f2b(tile[c4 + 1][nn]);
        o.z = f2b(tile[c4 + 2][nn]); o.w = f2b(tile[c4 + 3][nn]);
        *(ushort4*)(out + (size_t)(n0 + nn) * K + k0 + c4) = o;
    }
}

// ---------------------------------------------------------------- GEMM (A MxK, Bt NxK, both bf16)
// 128x128 tile, BK=64, 4 waves (2x2), 16x16x32 MFMA. m97 structure + source-side XOR swizzle.
template <bool F32OUT>
__global__ __launch_bounds__(256) void gemm_kernel(const u16* __restrict__ A,
                                                   const u16* __restrict__ Bt,
                                                   u16* __restrict__ Cb,
                                                   float* __restrict__ Cf,
                                                   int M, int N, int K) {
    __shared__ __align__(16) u16 As[128 * 64];
    __shared__ __align__(16) u16 Bs[128 * 64];
    int t = threadIdx.x;
    int lane = t & 63, w = t >> 6;
    int wr = w >> 1, wc = w & 1;
    int lr = lane & 15, hi = lane >> 4;
    int m0 = blockIdx.y * 128, n0 = blockIdx.x * 128;
    f32x4 acc[4][4] = {};
    int nk = K >> 6;
    for (int kt = 0; kt < nk; ++kt) {
        int k0 = kt << 6;
#pragma unroll
        for (int i = 0; i < 4; ++i) {
            int c = i * 256 + t;
            int row = c >> 3;
            int col8 = ((c & 7) ^ (row & 7)) << 3;
            int ldsb = (i * 256 + (t & ~63)) * 16;   // wave-uniform base
            gload16(A + (size_t)(m0 + row) * K + k0 + col8, (char*)As + ldsb);
            gload16(Bt + (size_t)(n0 + row) * K + k0 + col8, (char*)Bs + ldsb);
        }
        asm volatile("s_waitcnt vmcnt(0)" ::: "memory");
        __syncthreads();
#pragma unroll
        for (int kk = 0; kk < 64; kk += 32) {
            bf16x8 af[4], bfr[4];
#pragma unroll
            for (int i2 = 0; i2 < 4; ++i2) {
                int row = wr * 64 + i2 * 16 + lr;
                int byt = (row * 128 + (kk + 8 * hi) * 2) ^ ((row & 7) << 4);
                af[i2] = *(const bf16x8*)((const char*)As + byt);
                int rowb = wc * 64 + i2 * 16 + lr;
                int bytb = (rowb * 128 + (kk + 8 * hi) * 2) ^ ((rowb & 7) << 4);
                bfr[i2] = *(const bf16x8*)((const char*)Bs + bytb);
            }
#pragma unroll
            for (int im = 0; im < 4; ++im)
#pragma unroll
                for (int jn = 0; jn < 4; ++jn)
                    acc[im][jn] = mfma16(af[im], bfr[jn], acc[im][jn]);
        }
        __syncthreads();
    }
#pragma unroll
    for (int im = 0; im < 4; ++im)
#pragma unroll
        for (int jn = 0; jn < 4; ++jn)
#pragma unroll
            for (int r = 0; r < 4; ++r) {
                int m = m0 + wr * 64 + im * 16 + hi * 4 + r;
                int n = n0 + wc * 64 + jn * 16 + lr;
                if (F32OUT) Cf[(size_t)m * N + n] = acc[im][jn][r];
                else        Cb[(size_t)m * N + n] = f2b(acc[im][jn][r]);
            }
}

// ------------------------------- RoPE in-place on fused qkv (stride 6144) + roped-k f32 out
__global__ __launch_bounds__(256) void rope_kernel(u16* __restrict__ qkv,
                                                   float* __restrict__ outk) {
    int row = blockIdx.y;                    // b*2048 + l
    int p = blockIdx.x * 256 + threadIdx.x;  // 0..2559: 32 q-heads + 8 kv-heads, 64 pairs each
    int b = row >> 11, l = row & 2047;
    float freq = exp2f((float)(p & 63) * -0.2076205059304601f);  // 10000^(-i/64)
    float sv, cv; sincosf((float)l * freq, &sv, &cv);
    if (p < 2048) {
        int h = p >> 6, i = p & 63;
        size_t idx = (size_t)row * 6144 + h * 128 + 2 * i;
        u32 pr = *(const u32*)(qkv + idx);
        float x1 = b2f((u16)(pr & 0xffff)), x2 = b2f((u16)(pr >> 16));
        float o1 = x1 * cv + x2 * sv, o2 = x1 * sv - x2 * cv;
        *(u32*)(qkv + idx) = (u32)f2b(o1) | ((u32)f2b(o2) << 16);
    } else {
        int kvh = (p >> 6) - 32, i = p & 63;
        size_t idx = (size_t)row * 6144 + 4096 + kvh * 128 + 2 * i;
        u32 pr = *(const u32*)(qkv + idx);
        float x1 = b2f((u16)(pr & 0xffff)), x2 = b2f((u16)(pr >> 16));
        float o1 = x1 * cv + x2 * sv, o2 = x1 * sv - x2 * cv;
        *(u32*)(qkv + idx) = (u32)f2b(o1) | ((u32)f2b(o2) << 16);
#pragma unroll
        for (int r = 0; r < 4; ++r) {
            float2 o; o.x = o1; o.y = o2;
            *(float2*)(outk + ((size_t)((b * 32 + kvh * 4 + r) * 2048) + l) * 128 + 2 * i) = o;
        }
    }
}

// --------------------------------- V: write f32 x4 GQA copies to d_out + bf16 V^T for attention
__global__ __launch_bounds__(256) void vtrans_kernel(const u16* __restrict__ qkv,
                                                     u16* __restrict__ vt,
                                                     float* __restrict__ outv) {
    __shared__ u16 tile[64][65];
    int t = threadIdx.x;
    int l0 = blockIdx.x * 64, d0 = blockIdx.y * 64;
    int z = blockIdx.z, b = z >> 3, kvh = z & 7;
    int r = t >> 4, c4 = (t & 15) * 4;
#pragma unroll
    for (int i = 0; i < 4; ++i) {
        int l = l0 + i * 16 + r;
        ushort4 v = *(const ushort4*)(qkv + (size_t)(b * 2048 + l) * 6144 + 5120 + kvh * 128 + d0 + c4);
        tile[i * 16 + r][c4 + 0] = v.x; tile[i * 16 + r][c4 + 1] = v.y;
        tile[i * 16 + r][c4 + 2] = v.z; tile[i * 16 + r][c4 + 3] = v.w;
        float4 f; f.x = b2f(v.x); f.y = b2f(v.y); f.z = b2f(v.z); f.w = b2f(v.w);
#pragma unroll
        for (int rr = 0; rr < 4; ++rr)
            *(float4*)(outv + ((size_t)((b * 32 + kvh * 4 + rr) * 2048) + l) * 128 + d0 + c4) = f;
    }
    __syncthreads();
#pragma unroll
    for (int i = 0; i < 4; ++i) {
        int dn = i * 16 + r;
        ushort4 o;
        o.x = tile[c4 + 0][dn]; o.y = tile[c4 + 1][dn];
        o.z = tile[c4 + 2][dn]; o.w = tile[c4 + 3][dn];
        *(ushort4*)(vt + (size_t)((b * 8 + kvh) * 128 + d0 + dn) * 2048 + l0 + c4) = o;
    }
}

// ---------------------------------------------------------------- flash attention v2
// grid (16, 32, 2): block handles q-tile pair (31-bx, bx) sequentially = 33 K-tiles constant.
// K/V double-buffered, stage-issue before compute (2-phase T3 minimum), Q global->reg.
__global__ __launch_bounds__(256) void attn_kernel(const u16* __restrict__ qkv,
                                                   const u16* __restrict__ vt,
                                                   u16* __restrict__ ab) {
    __shared__ __align__(16) u16 Kbuf[2][64 * 128];   // K tile [kv][dh]
    __shared__ __align__(16) u16 Vbuf[2][128 * 64];   // V^T tile [dh][kv]
    __shared__ __align__(16) u16 Ps[4][16 * 64];      // per-wave P
    int t = threadIdx.x, lane = t & 63, w = t >> 6;
    int lr = lane & 15, hi = lane >> 4;
    int h = blockIdx.y, b = blockIdx.z, kvh = h >> 2;

    const u16* kbase = qkv + (size_t)(b * 2048) * 6144 + 4096 + kvh * 128;
    const u16* vtbase = vt + (size_t)((b * 8 + kvh) * 128) * 2048;

    auto stageKV = [&](int k0, int buf) {
#pragma unroll
        for (int i = 0; i < 4; ++i) {   // K: 64 rows x 128 cols
            int c = i * 256 + t;
            int row = c >> 4;
            int col8 = ((c & 15) ^ (row & 7)) << 3;
            gload16(kbase + (size_t)(k0 + row) * 6144 + col8,
                    (char*)Kbuf[buf] + (i * 256 + (t & ~63)) * 16);
        }
#pragma unroll
        for (int i = 0; i < 4; ++i) {   // V^T: 128 rows x 64 cols
            int c = i * 256 + t;
            int row = c >> 3;
            int col8 = ((c & 7) ^ (row & 7)) << 3;
            gload16(vtbase + (size_t)row * 2048 + k0 + col8,
                    (char*)Vbuf[buf] + (i * 256 + (t & ~63)) * 16);
        }
    };

    auto process = [&](int qblk) {
        int q0 = qblk * 64;
        int qr = w * 16 + lr;
        bf16x8 qf[4];
#pragma unroll
        for (int kki = 0; kki < 4; ++kki)   // Q direct global->reg
            qf[kki] = *(const bf16x8*)(qkv + (size_t)(b * 2048 + q0 + qr) * 6144 + h * 128 +
                                       kki * 32 + 8 * hi);
        f32x4 acc[8] = {};
        float mrun[4], lrun[4];
#pragma unroll
        for (int r = 0; r < 4; ++r) { mrun[r] = -1e30f; lrun[r] = 0.f; }

        int nt = qblk + 1;
        stageKV(0, 0);
        __syncthreads();
        int cur = 0;
        for (int kt = 0; kt < nt; ++kt) {
            if (kt + 1 < nt) stageKV((kt + 1) * 64, cur ^ 1);  // prefetch next tile
            __builtin_amdgcn_sched_barrier(0);

            const u16* Ks = Kbuf[cur];
            const u16* Vs = Vbuf[cur];
            // S = Q K^T
            f32x4 s[4] = {};
            __builtin_amdgcn_s_setprio(1);
#pragma unroll
            for (int kki = 0; kki < 4; ++kki) {
                bf16x8 kf[4];
#pragma unroll
                for (int fc = 0; fc < 4; ++fc) {
                    int kvr = fc * 16 + lr;
                    int byt = (kvr * 256 + (kki * 32 + 8 * hi) * 2) ^ ((kvr & 7) << 4);
                    kf[fc] = *(const bf16x8*)((const char*)Ks + byt);
                }
#pragma unroll
                for (int fc = 0; fc < 4; ++fc) s[fc] = mfma16(qf[kki], kf[fc], s[fc]);
            }
            __builtin_amdgcn_s_setprio(0);
            const float SC = 0.08838834764831845f;  // 1/sqrt(128)
            int diag = (kt == nt - 1);
#pragma unroll
            for (int fc = 0; fc < 4; ++fc)
#pragma unroll
                for (int r = 0; r < 4; ++r) {
                    float v = s[fc][r] * SC;
                    if (diag && (fc * 16 + lr) > (w * 16 + hi * 4 + r)) v = -1e30f;
                    s[fc][r] = v;
                }
            // online softmax
            float fr[4];
#pragma unroll
            for (int r = 0; r < 4; ++r) {
                float v = fmaxf(fmaxf(s[0][r], s[1][r]), fmaxf(s[2][r], s[3][r]));
                v = fmaxf(v, __shfl_xor(v, 1)); v = fmaxf(v, __shfl_xor(v, 2));
                v = fmaxf(v, __shfl_xor(v, 4)); v = fmaxf(v, __shfl_xor(v, 8));
                float mn = fmaxf(mrun[r], v);
                fr[r] = __expf(mrun[r] - mn);
                mrun[r] = mn;
            }
#pragma unroll
            for (int fc = 0; fc < 4; ++fc)
#pragma unroll
                for (int r = 0; r < 4; ++r) s[fc][r] = __expf(s[fc][r] - mrun[r]);
#pragma unroll
            for (int r = 0; r < 4; ++r) {
                float v = s[0][r] + s[1][r] + s[2][r] + s[3][r];
                v += __shfl_xor(v, 1); v += __shfl_xor(v, 2);
                v += __shfl_xor(v, 4); v += __shfl_xor(v, 8);
                lrun[r] = lrun[r] * fr[r] + v;
            }
#pragma unroll
            for (int dhf = 0; dhf < 8; ++dhf)
#pragma unroll
                for (int r = 0; r < 4; ++r) acc[dhf][r] *= fr[r];
            // P -> LDS (bf16, swizzled)
            u16* Pw = Ps[w];
#pragma unroll
            for (int fc = 0; fc < 4; ++fc)
#pragma unroll
                for (int r = 0; r < 4; ++r) {
                    int prow = hi * 4 + r, pcol = fc * 16 + lr;
                    int byt = (prow * 128 + pcol * 2) ^ ((prow & 7) << 4);
                    *(u16*)((char*)Pw + byt) = f2b(s[fc][r]);
                }
            asm volatile("s_waitcnt lgkmcnt(0)" ::: "memory");
            // O += P V
            __builtin_amdgcn_s_setprio(1);
#pragma unroll
            for (int kk2 = 0; kk2 < 2; ++kk2) {
                int bytp = (lr * 128 + (kk2 * 32 + 8 * hi) * 2) ^ ((lr & 7) << 4);
                bf16x8 pf = *(const bf16x8*)((const char*)Pw + bytp);
#pragma unroll
                for (int dhf = 0; dhf < 8; ++dhf) {
                    int dh = dhf * 16 + lr;
                    int bytv = (dh * 128 + (kk2 * 32 + 8 * hi) * 2) ^ ((dh & 7) << 4);
                    bf16x8 vf = *(const bf16x8*)((const char*)Vs + bytv);
                    acc[dhf] = mfma16(pf, vf, acc[dhf]);
                }
            }
            __builtin_amdgcn_s_setprio(0);
            __syncthreads();   // drains vmcnt -> prefetched tile ready; buf[cur] reads retired
            cur ^= 1;
        }
        // epilogue
#pragma unroll
        for (int dhf = 0; dhf < 8; ++dhf)
#pragma unroll
            for (int r = 0; r < 4; ++r) {
                int qrow = q0 + w * 16 + hi * 4 + r;
                int dh = dhf * 16 + lr;
                ab[(size_t)(b * 2048 + qrow) * 4096 + h * 128 + dh] = f2b(acc[dhf][r] / lrun[r]);
            }
    };

    process(31 - blockIdx.x);   // long tile first
    __syncthreads();
    process(blockIdx.x);
}

// ---------------------------------------------------------------- launch
extern "C" void kernel_launch(void* const* d_in, const int* in_sizes, int n_in,
                              void* d_out, int out_size, void* d_ws, size_t ws_size,
                              hipStream_t stream) {
    (void)in_sizes; (void)n_in; (void)out_size; (void)ws_size;
    const float* x  = (const float*)d_in[0];
    // d_in[1] = mask: exact causal tril(0 / -1e9) — handled analytically in attn_kernel
    const float* wq = (const float*)d_in[2];
    const float* wk = (const float*)d_in[3];
    const float* wv = (const float*)d_in[4];
    const float* wo = (const float*)d_in[5];

    char* ws = (char*)d_ws;
    u16* xb  = (u16*)(ws + 0);                       // 32 MiB; reused as ab after QKV GEMM
    u16* fBt = (u16*)(ws + 33554432);                // 48 MiB fused [wq^T; wk^T; wv^T]
    u16* qkv = (u16*)(ws + 83886080);                // 48 MiB [4096][6144]
    u16* vt  = (u16*)(ws + 134217728);               //  8 MiB -> total 142 MiB
    u16* ab  = xb;
    u16* wob = fBt;                                  // reuse fBt region after QKV GEMM

    float* out0 = (float*)d_out;
    float* outk = out0 + 16777216;
    float* outv = out0 + 33554432;

    convx_kernel<<<16384, 256, 0, stream>>>(x, xb);
    tconv_kernel<<<dim3(64, 64), 256, 0, stream>>>(wq, fBt, 4096, 4096);
    tconv_kernel<<<dim3(16, 64), 256, 0, stream>>>(wk, fBt + (size_t)4096 * 4096, 4096, 1024);
    tconv_kernel<<<dim3(16, 64), 256, 0, stream>>>(wv, fBt + (size_t)5120 * 4096, 4096, 1024);

    // fused QKV projection: [4096 x 4096] @ [4096 x 6144] -> qkv
    gemm_kernel<false><<<dim3(48, 32), 256, 0, stream>>>(xb, fBt, qkv, nullptr, 4096, 6144, 4096);

    tconv_kernel<<<dim3(64, 64), 256, 0, stream>>>(wo, wob, 4096, 4096);  // fBt dead now

    rope_kernel<<<dim3(10, 4096), 256, 0, stream>>>(qkv, outk);
    vtrans_kernel<<<dim3(32, 2, 16), 256, 0, stream>>>(qkv, vt, outv);

    attn_kernel<<<dim3(16, 32, 2), 256, 0, stream>>>(qkv, vt, ab);

    gemm_kernel<true><<<dim3(32, 32), 256, 0, stream>>>(ab, wob, nullptr, out0, 4096, 4096, 4096);
}

// Round 3
// 646.130 us; speedup vs baseline: 1.4422x; 1.0879x over previous
//
#include <hip/hip_runtime.h>

typedef unsigned short u16;
typedef unsigned int u32;
typedef float f32x4 __attribute__((ext_vector_type(4)));
typedef __bf16 bf16x8 __attribute__((ext_vector_type(8)));

#define DEV __device__ __forceinline__

DEV u16 f2b(float f) {
    union { float f; u32 u; } v; v.f = f;
    u32 r = v.u + 0x7fffu + ((v.u >> 16) & 1u);   // RNE
    return (u16)(r >> 16);
}
DEV float b2f(u16 b) {
    union { u32 u; float f; } v; v.u = ((u32)b) << 16;
    return v.f;
}

// global -> LDS direct (16B/lane). LDS dest must be wave-uniform base; HW adds lane*16.
DEV void gload16(const void* g, void* l) {
    __builtin_amdgcn_global_load_lds((const __attribute__((address_space(1))) void*)g,
                                     (__attribute__((address_space(3))) void*)l, 16, 0, 0);
}

DEV f32x4 mfma16(bf16x8 a, bf16x8 b, f32x4 c) {
    return __builtin_amdgcn_mfma_f32_16x16x32_bf16(a, b, c, 0, 0, 0);
}

// ---------------------------------------------------------------- convert x
__global__ __launch_bounds__(256) void convx_kernel(const float* __restrict__ in,
                                                    u16* __restrict__ out) {
    size_t i = ((size_t)blockIdx.x * 256 + threadIdx.x) * 4;
    float4 v = *(const float4*)(in + i);
    ushort4 o; o.x = f2b(v.x); o.y = f2b(v.y); o.z = f2b(v.z); o.w = f2b(v.w);
    *(ushort4*)(out + i) = o;
}

// ------------------------------------------- transpose + convert: (KxN f32) -> (NxK bf16)
__global__ __launch_bounds__(256) void tconv_kernel(const float* __restrict__ in,
                                                    u16* __restrict__ out, int K, int N) {
    __shared__ float tile[64][65];
    int t = threadIdx.x;
    int n0 = blockIdx.x * 64, k0 = blockIdx.y * 64;
    int r = t >> 4, c4 = (t & 15) * 4;
#pragma unroll
    for (int i = 0; i < 4; ++i) {
        float4 v = *(const float4*)(in + (size_t)(k0 + i * 16 + r) * N + n0 + c4);
        tile[i * 16 + r][c4 + 0] = v.x; tile[i * 16 + r][c4 + 1] = v.y;
        tile[i * 16 + r][c4 + 2] = v.z; tile[i * 16 + r][c4 + 3] = v.w;
    }
    __syncthreads();
#pragma unroll
    for (int i = 0; i < 4; ++i) {
        int nn = i * 16 + r;
        ushort4 o;
        o.x = f2b(tile[c4 + 0][nn]); o.y = f2b(tile[c4 + 1][nn]);
        o.z = f2b(tile[c4 + 2][nn]); o.w = f2b(tile[c4 + 3][nn]);
        *(ushort4*)(out + (size_t)(n0 + nn) * K + k0 + c4) = o;
    }
}

// ---------------------------------------------------------------- 256x256 8-phase GEMM
// A MxK, Bt NxK (both bf16). BK=64, 8 waves (2M x 4N), per-wave C = 128x64.
// LDS: 2 dbuf x 2 halves x [128][64] per operand = 128 KiB. Counted vmcnt(6) at
// K-tile boundaries only; per-phase raw s_barrier pairs; XOR(row&7)<<4 swizzle with
// source-side pre-swizzle for global_load_lds (proven 0-conflict in rounds 1-2).
// Stage placement is provably race-free: a half-slot is overwritten only in a phase
// after the phase where its reads complete (A reads end ph1 -> staged ph2; B reads
// end ph2 -> staged ph3; next-buf B1 staged ph0).
template <bool F32OUT>
__global__ __launch_bounds__(512, 2) void gemm256_kernel(const u16* __restrict__ A,
                                                         const u16* __restrict__ Bt,
                                                         u16* __restrict__ Cb,
                                                         float* __restrict__ Cf,
                                                         int M, int N, int K, int gx) {
    __shared__ __align__(16) u16 Asb[2][2][128 * 64];
    __shared__ __align__(16) u16 Bsb[2][2][128 * 64];
    (void)M;
    int t = threadIdx.x;
    int lane = t & 63, w = t >> 6;
    int wrM = w >> 2, wcN = w & 3;
    int lr = lane & 15, hi = lane >> 4;
    // bijective XCD swizzle (gridDim.x % 8 == 0 by launch config)
    int wg = blockIdx.x;
    int swz = (wg & 7) * ((int)gridDim.x >> 3) + (wg >> 3);
    int bx = swz % gx, by = swz / gx;
    int m0 = by * 256, n0 = bx * 256;
    int nk = K >> 6;

    auto stageA = [&](int X, int h) {
        const u16* src = A + (size_t)(m0 + h * 128) * K + X * 64;
        char* dst = (char*)&Asb[X & 1][h][0];
#pragma unroll
        for (int it = 0; it < 2; ++it) {
            int c = it * 512 + t;
            int row = c >> 3;
            int col8 = ((c & 7) ^ (row & 7)) << 3;
            gload16(src + (size_t)row * K + col8, dst + (it * 512 + (t & ~63)) * 16);
        }
    };
    auto stageB = [&](int X, int h) {
        const u16* src = Bt + (size_t)(n0 + h * 128) * K + X * 64;
        char* dst = (char*)&Bsb[X & 1][h][0];
#pragma unroll
        for (int it = 0; it < 2; ++it) {
            int c = it * 512 + t;
            int row = c >> 3;
            int col8 = ((c & 7) ^ (row & 7)) << 3;
            gload16(src + (size_t)row * K + col8, dst + (it * 512 + (t & ~63)) * 16);
        }
    };

    // prologue: tile0 complete + A0,A1,B0 of tile1 (B1(1) comes at kt=0 ph0)
    stageA(0, 0); stageA(0, 1); stageB(0, 0); stageB(0, 1);
    stageA(1, 0); stageA(1, 1); stageB(1, 0);
    asm volatile("s_waitcnt vmcnt(6)" ::: "memory");   // tile0's 8 loads landed
    __builtin_amdgcn_s_barrier();

    f32x4 acc[8][4] = {};
    for (int kt = 0; kt < nk; ++kt) {
        __builtin_amdgcn_sched_barrier(0);
        int p = kt & 1;
        const char* Ah = (const char*)&Asb[p][wrM][0];
        const char* Bh = (const char*)&Bsb[p][wcN >> 1][0];
        bool s1 = (kt + 1 < nk), s2 = (kt + 2 < nk);
        bf16x8 a[8][2], bb[2][2];

        // ---- ph0: read A mf0-3 + B nf0-1; stage B1(kt+1); MFMA quad(0,0)
#pragma unroll
        for (int mf = 0; mf < 4; ++mf)
#pragma unroll
            for (int ks = 0; ks < 2; ++ks) {
                int row = mf * 16 + lr;
                int byt = (row * 128 + ks * 64 + hi * 16) ^ ((row & 7) << 4);
                a[mf][ks] = *(const bf16x8*)(Ah + byt);
            }
#pragma unroll
        for (int nf = 0; nf < 2; ++nf)
#pragma unroll
            for (int ks = 0; ks < 2; ++ks) {
                int row = (wcN & 1) * 64 + nf * 16 + lr;
                int byt = (row * 128 + ks * 64 + hi * 16) ^ ((row & 7) << 4);
                bb[nf][ks] = *(const bf16x8*)(Bh + byt);
            }
        if (s1) stageB(kt + 1, 1);
        __builtin_amdgcn_s_barrier();
        __builtin_amdgcn_s_setprio(1);
#pragma unroll
        for (int mf = 0; mf < 4; ++mf)
#pragma unroll
            for (int nf = 0; nf < 2; ++nf)
#pragma unroll
                for (int ks = 0; ks < 2; ++ks)
                    acc[mf][nf] = mfma16(a[mf][ks], bb[nf][ks], acc[mf][nf]);
        __builtin_amdgcn_s_setprio(0);
        __builtin_amdgcn_s_barrier();

        // ---- ph1: read A mf4-7; MFMA quad(1,0)
#pragma unroll
        for (int mf = 4; mf < 8; ++mf)
#pragma unroll
            for (int ks = 0; ks < 2; ++ks) {
                int row = mf * 16 + lr;
                int byt = (row * 128 + ks * 64 + hi * 16) ^ ((row & 7) << 4);
                a[mf][ks] = *(const bf16x8*)(Ah + byt);
            }
        __builtin_amdgcn_s_barrier();
        __builtin_amdgcn_s_setprio(1);
#pragma unroll
        for (int mf = 4; mf < 8; ++mf)
#pragma unroll
            for (int nf = 0; nf < 2; ++nf)
#pragma unroll
                for (int ks = 0; ks < 2; ++ks)
                    acc[mf][nf] = mfma16(a[mf][ks], bb[nf][ks], acc[mf][nf]);
        __builtin_amdgcn_s_setprio(0);
        __builtin_amdgcn_s_barrier();

        // ---- ph2: read B nf2-3; stage A0,A1(kt+2); MFMA quad(1,1)
#pragma unroll
        for (int nf = 0; nf < 2; ++nf)
#pragma unroll
            for (int ks = 0; ks < 2; ++ks) {
                int row = (wcN & 1) * 64 + (nf + 2) * 16 + lr;
                int byt = (row * 128 + ks * 64 + hi * 16) ^ ((row & 7) << 4);
                bb[nf][ks] = *(const bf16x8*)(Bh + byt);
            }
        if (s2) { stageA(kt + 2, 0); stageA(kt + 2, 1); }
        __builtin_amdgcn_s_barrier();
        __builtin_amdgcn_s_setprio(1);
#pragma unroll
        for (int mf = 4; mf < 8; ++mf)
#pragma unroll
            for (int nf = 0; nf < 2; ++nf)
#pragma unroll
                for (int ks = 0; ks < 2; ++ks)
                    acc[mf][nf + 2] = mfma16(a[mf][ks], bb[nf][ks], acc[mf][nf + 2]);
        __builtin_amdgcn_s_setprio(0);
        __builtin_amdgcn_s_barrier();

        // ---- ph3: stage B0(kt+2); MFMA quad(0,1); boundary vmcnt
        if (s2) stageB(kt + 2, 0);
        __builtin_amdgcn_s_barrier();
        __builtin_amdgcn_s_setprio(1);
#pragma unroll
        for (int mf = 0; mf < 4; ++mf)
#pragma unroll
            for (int nf = 0; nf < 2; ++nf)
#pragma unroll
                for (int ks = 0; ks < 2; ++ks)
                    acc[mf][nf + 2] = mfma16(a[mf][ks], bb[nf][ks], acc[mf][nf + 2]);
        __builtin_amdgcn_s_setprio(0);
        if (s1) {
            if (s2) asm volatile("s_waitcnt vmcnt(6)" ::: "memory");  // kt+1 fully landed
            else    asm volatile("s_waitcnt vmcnt(0)" ::: "memory");  // tail: no newer loads
        }
        __builtin_amdgcn_s_barrier();
    }

    // epilogue
#pragma unroll
    for (int mf = 0; mf < 8; ++mf)
#pragma unroll
        for (int nf = 0; nf < 4; ++nf)
#pragma unroll
            for (int r = 0; r < 4; ++r) {
                int m = m0 + wrM * 128 + mf * 16 + hi * 4 + r;
                int n = n0 + wcN * 64 + nf * 16 + lr;
                if (F32OUT) Cf[(size_t)m * N + n] = acc[mf][nf][r];
                else        Cb[(size_t)m * N + n] = f2b(acc[mf][nf][r]);
            }
}

// ------------------------------- RoPE in-place on fused qkv (stride 6144) + roped-k f32 out
__global__ __launch_bounds__(256) void rope_kernel(u16* __restrict__ qkv,
                                                   float* __restrict__ outk) {
    int row = blockIdx.y;                    // b*2048 + l
    int p = blockIdx.x * 256 + threadIdx.x;  // 0..2559: 32 q-heads + 8 kv-heads, 64 pairs each
    int b = row >> 11, l = row & 2047;
    float freq = exp2f((float)(p & 63) * -0.2076205059304601f);  // 10000^(-i/64)
    float sv, cv; sincosf((float)l * freq, &sv, &cv);
    if (p < 2048) {
        int h = p >> 6, i = p & 63;
        size_t idx = (size_t)row * 6144 + h * 128 + 2 * i;
        u32 pr = *(const u32*)(qkv + idx);
        float x1 = b2f((u16)(pr & 0xffff)), x2 = b2f((u16)(pr >> 16));
        float o1 = x1 * cv + x2 * sv, o2 = x1 * sv - x2 * cv;
        *(u32*)(qkv + idx) = (u32)f2b(o1) | ((u32)f2b(o2) << 16);
    } else {
        int kvh = (p >> 6) - 32, i = p & 63;
        size_t idx = (size_t)row * 6144 + 4096 + kvh * 128 + 2 * i;
        u32 pr = *(const u32*)(qkv + idx);
        float x1 = b2f((u16)(pr & 0xffff)), x2 = b2f((u16)(pr >> 16));
        float o1 = x1 * cv + x2 * sv, o2 = x1 * sv - x2 * cv;
        *(u32*)(qkv + idx) = (u32)f2b(o1) | ((u32)f2b(o2) << 16);
#pragma unroll
        for (int r = 0; r < 4; ++r) {
            float2 o; o.x = o1; o.y = o2;
            *(float2*)(outk + ((size_t)((b * 32 + kvh * 4 + r) * 2048) + l) * 128 + 2 * i) = o;
        }
    }
}

// --------------------------------- V: write f32 x4 GQA copies to d_out + bf16 V^T for attention
__global__ __launch_bounds__(256) void vtrans_kernel(const u16* __restrict__ qkv,
                                                     u16* __restrict__ vt,
                                                     float* __restrict__ outv) {
    __shared__ u16 tile[64][65];
    int t = threadIdx.x;
    int l0 = blockIdx.x * 64, d0 = blockIdx.y * 64;
    int z = blockIdx.z, b = z >> 3, kvh = z & 7;
    int r = t >> 4, c4 = (t & 15) * 4;
#pragma unroll
    for (int i = 0; i < 4; ++i) {
        int l = l0 + i * 16 + r;
        ushort4 v = *(const ushort4*)(qkv + (size_t)(b * 2048 + l) * 6144 + 5120 + kvh * 128 + d0 + c4);
        tile[i * 16 + r][c4 + 0] = v.x; tile[i * 16 + r][c4 + 1] = v.y;
        tile[i * 16 + r][c4 + 2] = v.z; tile[i * 16 + r][c4 + 3] = v.w;
        float4 f; f.x = b2f(v.x); f.y = b2f(v.y); f.z = b2f(v.z); f.w = b2f(v.w);
#pragma unroll
        for (int rr = 0; rr < 4; ++rr)
            *(float4*)(outv + ((size_t)((b * 32 + kvh * 4 + rr) * 2048) + l) * 128 + d0 + c4) = f;
    }
    __syncthreads();
#pragma unroll
    for (int i = 0; i < 4; ++i) {
        int dn = i * 16 + r;
        ushort4 o;
        o.x = tile[c4 + 0][dn]; o.y = tile[c4 + 1][dn];
        o.z = tile[c4 + 2][dn]; o.w = tile[c4 + 3][dn];
        *(ushort4*)(vt + (size_t)((b * 8 + kvh) * 128 + d0 + dn) * 2048 + l0 + c4) = o;
    }
}

// ---------------------------------------------------------------- flash attention v2
// grid (16, 32, 2): block handles q-tile pair (31-bx, bx) sequentially = 33 K-tiles constant.
// K/V double-buffered, stage-issue before compute (2-phase T3 minimum), Q global->reg.
__global__ __launch_bounds__(256) void attn_kernel(const u16* __restrict__ qkv,
                                                   const u16* __restrict__ vt,
                                                   u16* __restrict__ ab) {
    __shared__ __align__(16) u16 Kbuf[2][64 * 128];   // K tile [kv][dh]
    __shared__ __align__(16) u16 Vbuf[2][128 * 64];   // V^T tile [dh][kv]
    __shared__ __align__(16) u16 Ps[4][16 * 64];      // per-wave P
    int t = threadIdx.x, lane = t & 63, w = t >> 6;
    int lr = lane & 15, hi = lane >> 4;
    int h = blockIdx.y, b = blockIdx.z, kvh = h >> 2;

    const u16* kbase = qkv + (size_t)(b * 2048) * 6144 + 4096 + kvh * 128;
    const u16* vtbase = vt + (size_t)((b * 8 + kvh) * 128) * 2048;

    auto stageKV = [&](int k0, int buf) {
#pragma unroll
        for (int i = 0; i < 4; ++i) {   // K: 64 rows x 128 cols
            int c = i * 256 + t;
            int row = c >> 4;
            int col8 = ((c & 15) ^ (row & 7)) << 3;
            gload16(kbase + (size_t)(k0 + row) * 6144 + col8,
                    (char*)Kbuf[buf] + (i * 256 + (t & ~63)) * 16);
        }
#pragma unroll
        for (int i = 0; i < 4; ++i) {   // V^T: 128 rows x 64 cols
            int c = i * 256 + t;
            int row = c >> 3;
            int col8 = ((c & 7) ^ (row & 7)) << 3;
            gload16(vtbase + (size_t)row * 2048 + k0 + col8,
                    (char*)Vbuf[buf] + (i * 256 + (t & ~63)) * 16);
        }
    };

    auto process = [&](int qblk) {
        int q0 = qblk * 64;
        int qr = w * 16 + lr;
        bf16x8 qf[4];
#pragma unroll
        for (int kki = 0; kki < 4; ++kki)   // Q direct global->reg
            qf[kki] = *(const bf16x8*)(qkv + (size_t)(b * 2048 + q0 + qr) * 6144 + h * 128 +
                                       kki * 32 + 8 * hi);
        f32x4 acc[8] = {};
        float mrun[4], lrun[4];
#pragma unroll
        for (int r = 0; r < 4; ++r) { mrun[r] = -1e30f; lrun[r] = 0.f; }

        int nt = qblk + 1;
        stageKV(0, 0);
        __syncthreads();
        int cur = 0;
        for (int kt = 0; kt < nt; ++kt) {
            if (kt + 1 < nt) stageKV((kt + 1) * 64, cur ^ 1);  // prefetch next tile
            __builtin_amdgcn_sched_barrier(0);

            const u16* Ks = Kbuf[cur];
            const u16* Vs = Vbuf[cur];
            // S = Q K^T
            f32x4 s[4] = {};
            __builtin_amdgcn_s_setprio(1);
#pragma unroll
            for (int kki = 0; kki < 4; ++kki) {
                bf16x8 kf[4];
#pragma unroll
                for (int fc = 0; fc < 4; ++fc) {
                    int kvr = fc * 16 + lr;
                    int byt = (kvr * 256 + (kki * 32 + 8 * hi) * 2) ^ ((kvr & 7) << 4);
                    kf[fc] = *(const bf16x8*)((const char*)Ks + byt);
                }
#pragma unroll
                for (int fc = 0; fc < 4; ++fc) s[fc] = mfma16(qf[kki], kf[fc], s[fc]);
            }
            __builtin_amdgcn_s_setprio(0);
            const float SC = 0.08838834764831845f;  // 1/sqrt(128)
            int diag = (kt == nt - 1);
#pragma unroll
            for (int fc = 0; fc < 4; ++fc)
#pragma unroll
                for (int r = 0; r < 4; ++r) {
                    float v = s[fc][r] * SC;
                    if (diag && (fc * 16 + lr) > (w * 16 + hi * 4 + r)) v = -1e30f;
                    s[fc][r] = v;
                }
            // online softmax
            float fr[4];
#pragma unroll
            for (int r = 0; r < 4; ++r) {
                float v = fmaxf(fmaxf(s[0][r], s[1][r]), fmaxf(s[2][r], s[3][r]));
                v = fmaxf(v, __shfl_xor(v, 1)); v = fmaxf(v, __shfl_xor(v, 2));
                v = fmaxf(v, __shfl_xor(v, 4)); v = fmaxf(v, __shfl_xor(v, 8));
                float mn = fmaxf(mrun[r], v);
                fr[r] = __expf(mrun[r] - mn);
                mrun[r] = mn;
            }
#pragma unroll
            for (int fc = 0; fc < 4; ++fc)
#pragma unroll
                for (int r = 0; r < 4; ++r) s[fc][r] = __expf(s[fc][r] - mrun[r]);
#pragma unroll
            for (int r = 0; r < 4; ++r) {
                float v = s[0][r] + s[1][r] + s[2][r] + s[3][r];
                v += __shfl_xor(v, 1); v += __shfl_xor(v, 2);
                v += __shfl_xor(v, 4); v += __shfl_xor(v, 8);
                lrun[r] = lrun[r] * fr[r] + v;
            }
#pragma unroll
            for (int dhf = 0; dhf < 8; ++dhf)
#pragma unroll
                for (int r = 0; r < 4; ++r) acc[dhf][r] *= fr[r];
            // P -> LDS (bf16, swizzled)
            u16* Pw = Ps[w];
#pragma unroll
            for (int fc = 0; fc < 4; ++fc)
#pragma unroll
                for (int r = 0; r < 4; ++r) {
                    int prow = hi * 4 + r, pcol = fc * 16 + lr;
                    int byt = (prow * 128 + pcol * 2) ^ ((prow & 7) << 4);
                    *(u16*)((char*)Pw + byt) = f2b(s[fc][r]);
                }
            asm volatile("s_waitcnt lgkmcnt(0)" ::: "memory");
            // O += P V
            __builtin_amdgcn_s_setprio(1);
#pragma unroll
            for (int kk2 = 0; kk2 < 2; ++kk2) {
                int bytp = (lr * 128 + (kk2 * 32 + 8 * hi) * 2) ^ ((lr & 7) << 4);
                bf16x8 pf = *(const bf16x8*)((const char*)Pw + bytp);
#pragma unroll
                for (int dhf = 0; dhf < 8; ++dhf) {
                    int dh = dhf * 16 + lr;
                    int bytv = (dh * 128 + (kk2 * 32 + 8 * hi) * 2) ^ ((dh & 7) << 4);
                    bf16x8 vf = *(const bf16x8*)((const char*)Vs + bytv);
                    acc[dhf] = mfma16(pf, vf, acc[dhf]);
                }
            }
            __builtin_amdgcn_s_setprio(0);
            __syncthreads();   // drains vmcnt -> prefetched tile ready; buf[cur] reads retired
            cur ^= 1;
        }
        // epilogue
#pragma unroll
        for (int dhf = 0; dhf < 8; ++dhf)
#pragma unroll
            for (int r = 0; r < 4; ++r) {
                int qrow = q0 + w * 16 + hi * 4 + r;
                int dh = dhf * 16 + lr;
                ab[(size_t)(b * 2048 + qrow) * 4096 + h * 128 + dh] = f2b(acc[dhf][r] / lrun[r]);
            }
    };

    process(31 - blockIdx.x);   // long tile first
    __syncthreads();
    process(blockIdx.x);
}

// ---------------------------------------------------------------- launch
extern "C" void kernel_launch(void* const* d_in, const int* in_sizes, int n_in,
                              void* d_out, int out_size, void* d_ws, size_t ws_size,
                              hipStream_t stream) {
    (void)in_sizes; (void)n_in; (void)out_size; (void)ws_size;
    const float* x  = (const float*)d_in[0];
    // d_in[1] = mask: exact causal tril(0 / -1e9) — handled analytically in attn_kernel
    const float* wq = (const float*)d_in[2];
    const float* wk = (const float*)d_in[3];
    const float* wv = (const float*)d_in[4];
    const float* wo = (const float*)d_in[5];

    char* ws = (char*)d_ws;
    u16* xb  = (u16*)(ws + 0);                       // 32 MiB; reused as ab after QKV GEMM
    u16* fBt = (u16*)(ws + 33554432);                // 48 MiB fused [wq^T; wk^T; wv^T]
    u16* qkv = (u16*)(ws + 83886080);                // 48 MiB [4096][6144]
    u16* vt  = (u16*)(ws + 134217728);               //  8 MiB -> total 142 MiB
    u16* ab  = xb;
    u16* wob = fBt;                                  // reuse fBt region after QKV GEMM

    float* out0 = (float*)d_out;
    float* outk = out0 + 16777216;
    float* outv = out0 + 33554432;

    convx_kernel<<<16384, 256, 0, stream>>>(x, xb);
    tconv_kernel<<<dim3(64, 64), 256, 0, stream>>>(wq, fBt, 4096, 4096);
    tconv_kernel<<<dim3(16, 64), 256, 0, stream>>>(wk, fBt + (size_t)4096 * 4096, 4096, 1024);
    tconv_kernel<<<dim3(16, 64), 256, 0, stream>>>(wv, fBt + (size_t)5120 * 4096, 4096, 1024);

    // fused QKV projection: [4096 x 4096] @ [4096 x 6144] -> qkv (grid 24x16 = 384, %8==0)
    gemm256_kernel<false><<<384, 512, 0, stream>>>(xb, fBt, qkv, nullptr, 4096, 6144, 4096, 24);

    tconv_kernel<<<dim3(64, 64), 256, 0, stream>>>(wo, wob, 4096, 4096);  // fBt dead now

    rope_kernel<<<dim3(10, 4096), 256, 0, stream>>>(qkv, outk);
    vtrans_kernel<<<dim3(32, 2, 16), 256, 0, stream>>>(qkv, vt, outv);

    attn_kernel<<<dim3(16, 32, 2), 256, 0, stream>>>(qkv, vt, ab);

    // output projection: [4096 x 4096] @ [4096 x 4096] -> out0 f32 (grid 16x16 = 256)
    gemm256_kernel<true><<<256, 512, 0, stream>>>(ab, wob, nullptr, out0, 4096, 4096, 4096, 16);
}